// Round 9
// baseline (283.533 us; speedup 1.0000x reference)
//
#include <hip/hip_runtime.h>
#include <stdint.h>

#define S_ 128
#define R_ 256
#define CM_ 256
#define H_ 8
#define CA_ 32
#define CZ_ 128

typedef unsigned short u16;
typedef __bf16 bf16x8 __attribute__((ext_vector_type(8)));
typedef float f32x4 __attribute__((ext_vector_type(4)));

#define LOG2E 1.4426950408889634f

__device__ __forceinline__ float bf2f(u16 u){ unsigned v = ((unsigned)u) << 16; float f; __builtin_memcpy(&f, &v, 4); return f; }
__device__ __forceinline__ u16 f2bf(float f){ __bf16 h = (__bf16)f; u16 u; __builtin_memcpy(&u, &h, 2); return u; }
__device__ __forceinline__ unsigned pkbf(float lo, float hi){
  unsigned r; asm("v_cvt_pk_bf16_f32 %0, %1, %2" : "=v"(r) : "v"(lo), "v"(hi)); return r;
}
__device__ __forceinline__ float fexp2(float x){
  float r; asm("v_exp_f32 %0, %1" : "=v"(r) : "v"(x)); return r;
}

__device__ __forceinline__ void gl16(const void* g, void* l){
  __builtin_amdgcn_global_load_lds((const __attribute__((address_space(1))) void*)g,
                                   (__attribute__((address_space(3))) void*)l, 16, 0, 0);
}

// ---------------- all 12 weight transposes in one launch ----------------
struct WSrc { const float* p[12]; };
__global__ __launch_bounds__(256) void transpose_all(WSrc srcs, u16* __restrict__ dst){
  int b = blockIdx.x, t = threadIdx.x;
  int job, idx;
  if(b < 2560){ job = b >> 8; idx = ((b & 255) << 8) + t; }
  else if(b < 3584){ job = 10; idx = ((b - 2560) << 8) + t; }
  else { job = 11; idx = ((b - 3584) << 8) + t; }
  int K = (job == 11) ? 1024 : 256;
  int N = (job == 10) ? 1024 : 256;
  int off;
  if(job < 10) off = job * 65536;
  else if(job == 10) off = 655360;
  else off = 917504;
  int k = idx / N, n = idx - k * N;
  // fold CA^-0.5 * log2(e) into wq so softmax can use exp2 directly
  float sc = (job == 0 || job == 5) ? (0.17677669529663687f * LOG2E) : 1.f;
  dst[off + n * K + k] = f2bf(srcs.p[job][idx] * sc);
}

// ---------------- LayerNorm over last dim 256 -> bf16 out; input fp32 or bf16 ----------------
template<bool BF16IN>
__global__ __launch_bounds__(256) void ln_kernel(const void* __restrict__ inv, const float* __restrict__ w,
                          const float* __restrict__ b, u16* __restrict__ out){
  int wv = threadIdx.x >> 6, lane = threadIdx.x & 63;
  long long row = (long long)blockIdx.x * 4 + wv;
  float vx, vy, vz, vw;
  if(BF16IN){
    ushort4 v4 = ((const ushort4*)((const u16*)inv + row * CM_))[lane];
    vx = bf2f(v4.x); vy = bf2f(v4.y); vz = bf2f(v4.z); vw = bf2f(v4.w);
  } else {
    float4 v4 = ((const float4*)((const float*)inv + row * CM_))[lane];
    vx = v4.x; vy = v4.y; vz = v4.z; vw = v4.w;
  }
  float s = vx + vy + vz + vw;
  for(int mo = 32; mo; mo >>= 1) s += __shfl_xor(s, mo, 64);
  float mu = s * (1.f / CM_);
  float dx = vx - mu, dy = vy - mu, dz = vz - mu, dw = vw - mu;
  float s2 = dx * dx + dy * dy + dz * dz + dw * dw;
  for(int mo = 32; mo; mo >>= 1) s2 += __shfl_xor(s2, mo, 64);
  float rstd = rsqrtf(s2 * (1.f / CM_) + 1e-5f);
  float4 w4 = ((const float4*)w)[lane];
  float4 b4 = ((const float4*)b)[lane];
  ushort4 st;
  st.x = f2bf(dx * rstd * w4.x + b4.x);
  st.y = f2bf(dy * rstd * w4.y + b4.y);
  st.z = f2bf(dz * rstd * w4.z + b4.z);
  st.w = f2bf(dw * rstd * w4.w + b4.w);
  *(ushort4*)(out + row * CM_ + lane * 4) = st;
}

// ---------------- pair bias v2: LN(z) -> LDS -> MFMA @ wb -> permuted bf16 (x log2e) ------
__global__ __launch_bounds__(256) void pair_bias_kernel(const float* __restrict__ z, const float* __restrict__ lnw,
                                 const float* __restrict__ lnb, const float* __restrict__ wb,
                                 u16* __restrict__ pb){
  __shared__ __attribute__((aligned(16))) unsigned char Xl[32 * 256];  // [32][128] bf16, XOR swz
  __shared__ __attribute__((aligned(16))) unsigned char Wl[16 * 256];  // [16 n][128 k] bf16, XOR swz
  const int t = threadIdx.x;
  const int wv = t >> 6, lane = t & 63, l15 = lane & 15, l4 = lane >> 4;
  const int r0 = blockIdx.x * 32;

  // stage wb -> Wl (transposed [n][k], heads 8..15 zero-padded)
  if(t < 128){
    const float4* wr = (const float4*)(wb + t * 8);
    float4 a = wr[0], bq = wr[1];
    u16 vals[8] = {f2bf(a.x), f2bf(a.y), f2bf(a.z), f2bf(a.w),
                   f2bf(bq.x), f2bf(bq.y), f2bf(bq.z), f2bf(bq.w)};
    #pragma unroll
    for(int n = 0; n < 8; n++){
      *(u16*)(Wl + ((n * 256 + t * 2) ^ ((n & 7) << 4))) = vals[n];
      *(u16*)(Wl + (((n + 8) * 256 + t * 2) ^ ((n & 7) << 4))) = 0;
    }
  }
  // LN: row = wv*8 + (lane>>3), 16 c per lane
  {
    int row = wv * 8 + (lane >> 3);
    int c0 = (lane & 7) * 16;
    const float4* rp = (const float4*)(z + (long long)(r0 + row) * CZ_ + c0);
    float4 v0 = rp[0], v1 = rp[1], v2 = rp[2], v3 = rp[3];
    float s = v0.x + v0.y + v0.z + v0.w + v1.x + v1.y + v1.z + v1.w
            + v2.x + v2.y + v2.z + v2.w + v3.x + v3.y + v3.z + v3.w;
    s += __shfl_xor(s, 1, 64); s += __shfl_xor(s, 2, 64); s += __shfl_xor(s, 4, 64);
    float mu = s * (1.f / CZ_);
    float d[16] = {v0.x - mu, v0.y - mu, v0.z - mu, v0.w - mu,
                   v1.x - mu, v1.y - mu, v1.z - mu, v1.w - mu,
                   v2.x - mu, v2.y - mu, v2.z - mu, v2.w - mu,
                   v3.x - mu, v3.y - mu, v3.z - mu, v3.w - mu};
    float s2 = 0.f;
    #pragma unroll
    for(int i = 0; i < 16; i++) s2 += d[i] * d[i];
    s2 += __shfl_xor(s2, 1, 64); s2 += __shfl_xor(s2, 2, 64); s2 += __shfl_xor(s2, 4, 64);
    float rstd = rsqrtf(s2 * (1.f / CZ_) + 1e-5f);
    const float4* wp = (const float4*)(lnw + c0);
    const float4* bp = (const float4*)(lnb + c0);
    float x[16];
    #pragma unroll
    for(int i = 0; i < 4; i++){
      float4 w4 = wp[i], b4 = bp[i];
      x[i * 4 + 0] = d[i * 4 + 0] * rstd * w4.x + b4.x;
      x[i * 4 + 1] = d[i * 4 + 1] * rstd * w4.y + b4.y;
      x[i * 4 + 2] = d[i * 4 + 2] * rstd * w4.z + b4.z;
      x[i * 4 + 3] = d[i * 4 + 3] * rstd * w4.w + b4.w;
    }
    uint4 p0, p1;
    p0.x = pkbf(x[0], x[1]);  p0.y = pkbf(x[2], x[3]);
    p0.z = pkbf(x[4], x[5]);  p0.w = pkbf(x[6], x[7]);
    p1.x = pkbf(x[8], x[9]);  p1.y = pkbf(x[10], x[11]);
    p1.z = pkbf(x[12], x[13]); p1.w = pkbf(x[14], x[15]);
    *(uint4*)(Xl + ((row * 256 + c0 * 2) ^ ((row & 7) << 4))) = p0;
    *(uint4*)(Xl + ((row * 256 + c0 * 2 + 16) ^ ((row & 7) << 4))) = p1;
  }
  __syncthreads();
  // MFMA projection: waves 0,1 each do a 16-row tile x 4 K-steps
  if(wv < 2){
    f32x4 acc = {0.f, 0.f, 0.f, 0.f};
    #pragma unroll
    for(int ks = 0; ks < 4; ks++){
      int rowA = wv * 16 + l15;
      bf16x8 a = *(const bf16x8*)(Xl + ((rowA * 256 + l4 * 16 + ks * 64) ^ ((rowA & 7) << 4)));
      bf16x8 b = *(const bf16x8*)(Wl + ((l15 * 256 + l4 * 16 + ks * 64) ^ ((l15 & 7) << 4)));
      acc = __builtin_amdgcn_mfma_f32_16x16x32_bf16(a, b, acc, 0, 0, 0);
    }
    if(l15 < 8){
      #pragma unroll
      for(int r = 0; r < 4; r++){
        int rowg = r0 + wv * 16 + l4 * 4 + r;
        int q = rowg >> 8, k = rowg & 255;
        int off = (((l15 * 16 + (q >> 4)) * 16 + (k >> 4)) << 10)
                + ((((q >> 2) & 3) * 16 + (k & 15)) << 2) + (q & 3);
        pb[off] = f2bf(acc[r] * LOG2E);
      }
    }
  }
}

// ---------------- MFMA GEMM 128x128 tile, BK=64, global_load_lds + XOR swizzle ----------------
// RESMODE: 0 none, 1 fp32 residual, 2 bf16 residual.
template<bool HAS_BIAS, bool HAS_SIG, bool RELU, int RESMODE, bool F32OUT>
__global__ __launch_bounds__(256) void gemm128(
    const u16* __restrict__ A, const u16* __restrict__ Wt,
    const float* __restrict__ bias, const void* __restrict__ res,
    void* __restrict__ outv, int M, int N, int K, int sigStart){
  __shared__ __attribute__((aligned(16))) unsigned char Ab[16384];
  __shared__ __attribute__((aligned(16))) unsigned char Bb[16384];
  const int t = threadIdx.x;
  const int wv = t >> 6, lane = t & 63, l15 = lane & 15, l4 = lane >> 4;
  const int wm = wv >> 1, wn = wv & 1;
  const unsigned flat = blockIdx.y * gridDim.x + blockIdx.x;
  const unsigned NB = gridDim.x, mper = gridDim.y >> 3;
  const unsigned xcd = flat & 7, j = flat >> 3;
  const unsigned n_blk = j % NB, m_blk = xcd * mper + j / NB;
  const long long m0 = (long long)m_blk * 128;
  const int n0 = n_blk * 128;
  const int srow = t >> 3;
  const int ksw  = ((t & 7) ^ (srow & 7)) * 8;
  const u16* Ag = A  + (m0 + srow) * (long long)K + ksw;
  const u16* Bg = Wt + (long long)(n0 + srow) * K + ksw;
  f32x4 acc[4][4] = {};
  for(int kk = 0; kk < K; kk += 64){
    #pragma unroll
    for(int i = 0; i < 4; i++){
      gl16(Ag + (long long)i * 32 * K + kk, Ab + wv * 1024 + lane * 16 + i * 4096);
      gl16(Bg + (long long)i * 32 * K + kk, Bb + wv * 1024 + lane * 16 + i * 4096);
    }
    asm volatile("s_waitcnt vmcnt(0)" ::: "memory");
    __syncthreads();
    #pragma unroll
    for(int kh = 0; kh < 2; kh++){
      bf16x8 af[4], bq[4];
      #pragma unroll
      for(int mt = 0; mt < 4; mt++){
        int rr = wm * 64 + mt * 16 + l15;
        af[mt] = *(const bf16x8*)(Ab + rr * 128 + ((kh * 64 + l4 * 16) ^ ((rr & 7) << 4)));
      }
      #pragma unroll
      for(int nt = 0; nt < 4; nt++){
        int rr = wn * 64 + nt * 16 + l15;
        bq[nt] = *(const bf16x8*)(Bb + rr * 128 + ((kh * 64 + l4 * 16) ^ ((rr & 7) << 4)));
      }
      #pragma unroll
      for(int mt = 0; mt < 4; mt++)
        #pragma unroll
        for(int nt = 0; nt < 4; nt++)
          acc[mt][nt] = __builtin_amdgcn_mfma_f32_16x16x32_bf16(af[mt], bq[nt], acc[mt][nt], 0, 0, 0);
    }
    __syncthreads();
  }
  float bnt[4]; bool sg[4];
  #pragma unroll
  for(int nt = 0; nt < 4; nt++){
    int ncol = n0 + wn * 64 + nt * 16 + l15;
    bnt[nt] = 0.f; sg[nt] = false;
    if(HAS_BIAS){
      if(HAS_SIG){ sg[nt] = (ncol >= sigStart); bnt[nt] = sg[nt] ? bias[ncol - sigStart] : 0.f; }
      else bnt[nt] = bias[ncol];
    }
  }
  #pragma unroll
  for(int mt = 0; mt < 4; mt++){
    #pragma unroll
    for(int r = 0; r < 4; r++){
      long long mrow = m0 + wm * 64 + mt * 16 + l4 * 4 + r;
      #pragma unroll
      for(int nt = 0; nt < 4; nt++){
        int ncol = n0 + wn * 64 + nt * 16 + l15;
        float v = acc[mt][nt][r] + bnt[nt];
        if(HAS_SIG){ if(sg[nt]) v = 1.f / (1.f + __expf(-v)); }
        if(RELU) v = v > 0.f ? v : 0.f;
        if(RESMODE == 1) v += ((const float*)res)[mrow * N + ncol];
        if(RESMODE == 2) v += bf2f(((const u16*)res)[mrow * N + ncol]);
        if(F32OUT) ((float*)outv)[mrow * N + ncol] = v;
        else       ((u16*)outv)[mrow * N + ncol] = f2bf(v);
      }
    }
  }
}

// ---------------- fused attention: K+V^T in LDS, exp2 softmax, chunk-permuted P ----------------
// SPLIT blocks per (outer,h) share staging; each covers L/SPLIT queries (block refill + latency hiding).
template<int L, int SPLIT, bool HAS_BIAS>
__global__ __launch_bounds__(256) void atten_kernel(
    const u16* __restrict__ qg, const u16* __restrict__ kg, const u16* __restrict__ vg,
    const u16* __restrict__ gg, const u16* __restrict__ pb, const float* __restrict__ mask,
    u16* __restrict__ og,
    long long obase_mul, long long tstride, long long obase_o, long long ostride,
    long long mbase_mul, int mstride){
  __shared__ __attribute__((aligned(16))) unsigned char smem[L * 128 + 8192];
  unsigned char* Kl = smem;              // [L][32] bf16, XOR swizzle
  unsigned char* Vt = smem + L * 64;     // [32][L] bf16 (V^T, k-permuted), swizzled
  unsigned char* Pl = smem + L * 128;    // per-wave [16][64] bf16 chunk

  const int t = threadIdx.x;
  const int wv = t >> 6, lane = t & 63, l15 = lane & 15, l4 = lane >> 4;
  const int h = blockIdx.x & 7;
  const int g2 = blockIdx.x >> 3;
  const int sp = g2 % SPLIT;
  const int outer = g2 / SPLIT;
  const long long base  = (long long)outer * obase_mul + h * CA_;
  const long long baseo = (long long)outer * obase_o  + h * CA_;
  const long long mb = (long long)outer * mbase_mul;
  const int KT = L / 16, NC = L / 64, QB = L / SPLIT;

  // stage K: [L][32] swizzled
  #pragma unroll
  for(int j = 0; j < L * 4; j += 256){
    int cid = j + t;
    int row = cid >> 2, ko = cid & 3;
    int4 kv = *(const int4*)(kg + base + (long long)row * tstride + ko * 8);
    *(int4*)(Kl + ((row * 64 + ko * 16) ^ ((row & 7) << 4))) = kv;
  }
  // stage V transposed (k-permuted)
  if(t < L){
    __attribute__((aligned(16))) u16 tmp[32];
    const u16* vp = vg + base + (long long)t * tstride;
    #pragma unroll
    for(int j2 = 0; j2 < 4; j2++) ((int4*)tmp)[j2] = *(const int4*)(vp + j2 * 8);
    int kp = (t >> 6) * 64 + (t & 15) * 4 + ((t >> 4) & 3);   // permuted key index
    #pragma unroll
    for(int c = 0; c < 32; c++)
      *(u16*)(Vt + (((c * L + kp) * 2) ^ ((c & 7) << 4))) = tmp[c];
  }
  __syncthreads();

  float mskb[L / 16];
  #pragma unroll
  for(int kt = 0; kt < KT; kt++)
    mskb[kt] = (mask[mb + (long long)(kt * 16 + l15) * mstride] - 1.f) * (1e9f * LOG2E);

  unsigned char* Pw = Pl + wv * 2048;
  #pragma unroll
  for(int qt = 0; qt < QB / 64; qt++){
    const int qrow0 = sp * QB + wv * (QB / 4) + qt * 16;
    bf16x8 aq = *(const bf16x8*)(qg + base + (long long)(qrow0 + l15) * tstride + l4 * 8);
    f32x4 lac[L / 16];
    #pragma unroll
    for(int kt = 0; kt < KT; kt++){
      int kr = kt * 16 + l15;
      bf16x8 bk = *(const bf16x8*)(Kl + ((kr * 64 + l4 * 16) ^ ((kr & 7) << 4)));
      f32x4 zz = {0.f, 0.f, 0.f, 0.f};
      lac[kt] = __builtin_amdgcn_mfma_f32_16x16x32_bf16(aq, bk, zz, 0, 0, 0);
    }
    // merged bias + mask + exp2 + sum (log2e folded into q-scale/bias/mask)
    const u16* tile = HAS_BIAS ? (pb + (((h * 16 + (qrow0 >> 4)) * 16) << 10) + lane * 4) : nullptr;
    float sm[4] = {1e-30f, 1e-30f, 1e-30f, 1e-30f};
    #pragma unroll
    for(int kt = 0; kt < KT; kt++){
      float mm = mskb[kt];
      if(HAS_BIAS){
        ushort4 b4 = *(const ushort4*)(tile + (kt << 10));
        lac[kt][0] = fexp2(lac[kt][0] + mm + bf2f(b4.x));
        lac[kt][1] = fexp2(lac[kt][1] + mm + bf2f(b4.y));
        lac[kt][2] = fexp2(lac[kt][2] + mm + bf2f(b4.z));
        lac[kt][3] = fexp2(lac[kt][3] + mm + bf2f(b4.w));
      } else {
        #pragma unroll
        for(int r = 0; r < 4; r++) lac[kt][r] = fexp2(lac[kt][r] + mm);
      }
      #pragma unroll
      for(int r = 0; r < 4; r++) sm[r] += lac[kt][r];
    }
    #pragma unroll
    for(int mo = 1; mo < 16; mo <<= 1)
      #pragma unroll
      for(int r = 0; r < 4; r++) sm[r] += __shfl_xor(sm[r], mo, 64);
    float inv[4];
    #pragma unroll
    for(int r = 0; r < 4; r++) inv[r] = 1.f / sm[r];
    // chunked PV on unnormalized P; lane's 4 chunk-values contiguous at col l15*4
    f32x4 oac[2] = {{0,0,0,0},{0,0,0,0}};
    #pragma unroll
    for(int ch = 0; ch < NC; ch++){
      asm volatile("" ::: "memory");
      #pragma unroll
      for(int r = 0; r < 4; r++){
        int qp = l4 * 4 + r;
        uint2 pk2;
        pk2.x = pkbf(lac[ch * 4 + 0][r], lac[ch * 4 + 1][r]);
        pk2.y = pkbf(lac[ch * 4 + 2][r], lac[ch * 4 + 3][r]);
        *(uint2*)(Pw + qp * 128 + ((l15 * 8) ^ ((qp & 7) << 4))) = pk2;
      }
      asm volatile("s_waitcnt lgkmcnt(0)" ::: "memory");
      #pragma unroll
      for(int ksl = 0; ksl < 2; ksl++){
        bf16x8 ap = *(const bf16x8*)(Pw + l15 * 128 + ((ksl * 64 + l4 * 16) ^ ((l15 & 7) << 4)));
        #pragma unroll
        for(int ct = 0; ct < 2; ct++){
          int c = ct * 16 + l15;
          bf16x8 bv = *(const bf16x8*)(Vt + (((c * L + ch * 64 + ksl * 32 + l4 * 8) * 2) ^ ((c & 7) << 4)));
          oac[ct] = __builtin_amdgcn_mfma_f32_16x16x32_bf16(ap, bv, oac[ct], 0, 0, 0);
        }
      }
    }
    // epilogue: normalize, multiply sigmoid-gate, store
    #pragma unroll
    for(int ct = 0; ct < 2; ct++)
      #pragma unroll
      for(int r = 0; r < 4; r++){
        int qi = qrow0 + l4 * 4 + r, c = ct * 16 + l15;
        float g = bf2f(gg[base + (long long)qi * tstride + c]);
        og[baseo + (long long)qi * ostride + c] = f2bf(oac[ct][r] * inv[r] * g);
      }
  }
}

extern "C" void kernel_launch(void* const* d_in, const int* in_sizes, int n_in,
                              void* d_out, int out_size, void* d_ws, size_t ws_size,
                              hipStream_t stream){
  const float* m        = (const float*)d_in[0];
  const float* m_mask   = (const float*)d_in[1];
  const float* z        = (const float*)d_in[2];
  const float* row_ln_w = (const float*)d_in[3];
  const float* row_ln_b = (const float*)d_in[4];
  const float* row_z_ln_w = (const float*)d_in[5];
  const float* row_z_ln_b = (const float*)d_in[6];
  const float* row_bg   = (const float*)d_in[12];
  const float* row_bo   = (const float*)d_in[14];
  const float* col_ln_w = (const float*)d_in[15];
  const float* col_ln_b = (const float*)d_in[16];
  const float* col_bg   = (const float*)d_in[21];
  const float* col_bo   = (const float*)d_in[23];
  const float* tr_ln_w  = (const float*)d_in[24];
  const float* tr_ln_b  = (const float*)d_in[25];
  const float* tr_b1    = (const float*)d_in[27];
  const float* tr_b2    = (const float*)d_in[29];
  float* out = (float*)d_out;
  char* ws = (char*)d_ws;

  // buffer plan (bf16 residual stream, no ws growth):
  //  bx  [32768][256]: ln1-out -> m1 (bf16) -> ln3-out
  //  fq  [32768][1024]: QKVG (row) -> QKVG (col); then fq[0..8.4M) = m2, fq+8.4M.. = h1
  //  t_o [32768][256]: atten1-out -> ln2-out -> atten2-out
  u16* bx  = (u16*)ws;
  u16* fq  = bx + 8388608;
  u16* t_o = fq + 33554432;
  u16* pb  = t_o + 8388608;               // permuted pair bias, 2M bf16
  u16* wt  = pb + 2097152;                // transposed weights
  u16* m2  = fq;                          // [32768][256] bf16 (after col QKVG consumed)
  u16* h1  = fq + 8388608;                // [32768][1024] bf16

  WSrc srcs;
  srcs.p[0] = (const float*)d_in[7];   // row_wq
  srcs.p[1] = (const float*)d_in[8];   // row_wk
  srcs.p[2] = (const float*)d_in[9];   // row_wv
  srcs.p[3] = (const float*)d_in[11];  // row_wg
  srcs.p[4] = (const float*)d_in[13];  // row_wo
  srcs.p[5] = (const float*)d_in[17];  // col_wq
  srcs.p[6] = (const float*)d_in[18];  // col_wk
  srcs.p[7] = (const float*)d_in[19];  // col_wv
  srcs.p[8] = (const float*)d_in[20];  // col_wg
  srcs.p[9] = (const float*)d_in[22];  // col_wo
  srcs.p[10] = (const float*)d_in[26]; // tr_w1
  srcs.p[11] = (const float*)d_in[28]; // tr_w2

  dim3 b256(256);
  transpose_all<<<dim3(4608), b256, 0, stream>>>(srcs, wt);
  pair_bias_kernel<<<dim3(2048), b256, 0, stream>>>(z, row_z_ln_w, row_z_ln_b,
                                                    (const float*)d_in[10], pb);

  // ---- row attention ----
  ln_kernel<false><<<dim3(8192), b256, 0, stream>>>(m, row_ln_w, row_ln_b, bx);
  gemm128<true,true,false,0,false><<<dim3(8,256), b256, 0, stream>>>(
      bx, wt, row_bg, nullptr, fq, 32768, 1024, 256, 768);
  atten_kernel<256,2,true><<<dim3(2048), b256, 0, stream>>>(
      fq, fq + 256, fq + 512, fq + 768, pb, m_mask, t_o,
      262144, 1024, 65536, 256, 256, 1);
  gemm128<true,false,false,1,false><<<dim3(2,256), b256, 0, stream>>>(
      t_o, wt + 262144, row_bo, m, bx, 32768, 256, 256, 0);   // m1 -> bx (bf16)

  // ---- column attention ----
  ln_kernel<true><<<dim3(8192), b256, 0, stream>>>(bx, col_ln_w, col_ln_b, t_o);
  gemm128<true,true,false,0,false><<<dim3(8,256), b256, 0, stream>>>(
      t_o, wt + 327680, col_bg, nullptr, fq, 32768, 1024, 256, 768);
  atten_kernel<128,2,false><<<dim3(4096), b256, 0, stream>>>(
      fq, fq + 256, fq + 512, fq + 768, nullptr, m_mask, t_o,
      1024, 262144, 256, 65536, 1, 256);
  gemm128<true,false,false,2,false><<<dim3(2,256), b256, 0, stream>>>(
      t_o, wt + 589824, col_bo, bx, m2, 32768, 256, 256, 0);  // m2 -> fq[0..] (bf16)

  // ---- transition ----
  ln_kernel<true><<<dim3(8192), b256, 0, stream>>>(m2, tr_ln_w, tr_ln_b, bx);
  gemm128<true,false,true,0,false><<<dim3(8,256), b256, 0, stream>>>(
      bx, wt + 655360, tr_b1, nullptr, h1, 32768, 1024, 256, 0);
  gemm128<true,false,false,2,true><<<dim3(2,256), b256, 0, stream>>>(
      h1, wt + 917504, tr_b2, m2, out, 32768, 256, 1024, 0);
}

// Round 10
// 268.189 us; speedup vs baseline: 1.0572x; 1.0572x over previous
//
#include <hip/hip_runtime.h>
#include <stdint.h>

#define S_ 128
#define R_ 256
#define CM_ 256
#define H_ 8
#define CA_ 32
#define CZ_ 128

typedef unsigned short u16;
typedef __bf16 bf16x8 __attribute__((ext_vector_type(8)));
typedef float f32x4 __attribute__((ext_vector_type(4)));

#define LOG2E 1.4426950408889634f

__device__ __forceinline__ float bf2f(u16 u){ unsigned v = ((unsigned)u) << 16; float f; __builtin_memcpy(&f, &v, 4); return f; }
__device__ __forceinline__ u16 f2bf(float f){ __bf16 h = (__bf16)f; u16 u; __builtin_memcpy(&u, &h, 2); return u; }
__device__ __forceinline__ unsigned pkbf(float lo, float hi){
  unsigned r; asm("v_cvt_pk_bf16_f32 %0, %1, %2" : "=v"(r) : "v"(lo), "v"(hi)); return r;
}
__device__ __forceinline__ float fexp2(float x){
  float r; asm("v_exp_f32 %0, %1" : "=v"(r) : "v"(x)); return r;
}

__device__ __forceinline__ void gl16(const void* g, void* l){
  __builtin_amdgcn_global_load_lds((const __attribute__((address_space(1))) void*)g,
                                   (__attribute__((address_space(3))) void*)l, 16, 0, 0);
}

// ---------------- all 12 weight transposes in one launch ----------------
struct WSrc { const float* p[12]; };
__global__ __launch_bounds__(256) void transpose_all(WSrc srcs, u16* __restrict__ dst){
  int b = blockIdx.x, t = threadIdx.x;
  int job, idx;
  if(b < 2560){ job = b >> 8; idx = ((b & 255) << 8) + t; }
  else if(b < 3584){ job = 10; idx = ((b - 2560) << 8) + t; }
  else { job = 11; idx = ((b - 3584) << 8) + t; }
  int K = (job == 11) ? 1024 : 256;
  int N = (job == 10) ? 1024 : 256;
  int off;
  if(job < 10) off = job * 65536;
  else if(job == 10) off = 655360;
  else off = 917504;
  int k = idx / N, n = idx - k * N;
  // fold CA^-0.5 * log2(e) into wq so softmax can use exp2 directly
  float sc = (job == 0 || job == 5) ? (0.17677669529663687f * LOG2E) : 1.f;
  dst[off + n * K + k] = f2bf(srcs.p[job][idx] * sc);
}

// ---------------- LayerNorm over last dim 256 -> bf16 out; input fp32 or bf16 ----------------
template<bool BF16IN>
__global__ __launch_bounds__(256) void ln_kernel(const void* __restrict__ inv, const float* __restrict__ w,
                          const float* __restrict__ b, u16* __restrict__ out){
  int wv = threadIdx.x >> 6, lane = threadIdx.x & 63;
  long long row = (long long)blockIdx.x * 4 + wv;
  float vx, vy, vz, vw;
  if(BF16IN){
    ushort4 v4 = ((const ushort4*)((const u16*)inv + row * CM_))[lane];
    vx = bf2f(v4.x); vy = bf2f(v4.y); vz = bf2f(v4.z); vw = bf2f(v4.w);
  } else {
    float4 v4 = ((const float4*)((const float*)inv + row * CM_))[lane];
    vx = v4.x; vy = v4.y; vz = v4.z; vw = v4.w;
  }
  float s = vx + vy + vz + vw;
  for(int mo = 32; mo; mo >>= 1) s += __shfl_xor(s, mo, 64);
  float mu = s * (1.f / CM_);
  float dx = vx - mu, dy = vy - mu, dz = vz - mu, dw = vw - mu;
  float s2 = dx * dx + dy * dy + dz * dz + dw * dw;
  for(int mo = 32; mo; mo >>= 1) s2 += __shfl_xor(s2, mo, 64);
  float rstd = rsqrtf(s2 * (1.f / CM_) + 1e-5f);
  float4 w4 = ((const float4*)w)[lane];
  float4 b4 = ((const float4*)b)[lane];
  ushort4 st;
  st.x = f2bf(dx * rstd * w4.x + b4.x);
  st.y = f2bf(dy * rstd * w4.y + b4.y);
  st.z = f2bf(dz * rstd * w4.z + b4.z);
  st.w = f2bf(dw * rstd * w4.w + b4.w);
  *(ushort4*)(out + row * CM_ + lane * 4) = st;
}

// ---------------- pair bias v2: LN(z) -> LDS -> MFMA @ wb -> permuted bf16 (x log2e) ------
__global__ __launch_bounds__(256) void pair_bias_kernel(const float* __restrict__ z, const float* __restrict__ lnw,
                                 const float* __restrict__ lnb, const float* __restrict__ wb,
                                 u16* __restrict__ pb){
  __shared__ __attribute__((aligned(16))) unsigned char Xl[32 * 256];  // [32][128] bf16, XOR swz
  __shared__ __attribute__((aligned(16))) unsigned char Wl[16 * 256];  // [16 n][128 k] bf16, XOR swz
  const int t = threadIdx.x;
  const int wv = t >> 6, lane = t & 63, l15 = lane & 15, l4 = lane >> 4;
  const int r0 = blockIdx.x * 32;

  // stage wb -> Wl (transposed [n][k], heads 8..15 zero-padded)
  if(t < 128){
    const float4* wr = (const float4*)(wb + t * 8);
    float4 a = wr[0], bq = wr[1];
    u16 vals[8] = {f2bf(a.x), f2bf(a.y), f2bf(a.z), f2bf(a.w),
                   f2bf(bq.x), f2bf(bq.y), f2bf(bq.z), f2bf(bq.w)};
    #pragma unroll
    for(int n = 0; n < 8; n++){
      *(u16*)(Wl + ((n * 256 + t * 2) ^ ((n & 7) << 4))) = vals[n];
      *(u16*)(Wl + (((n + 8) * 256 + t * 2) ^ ((n & 7) << 4))) = 0;
    }
  }
  // LN: row = wv*8 + (lane>>3), 16 c per lane
  {
    int row = wv * 8 + (lane >> 3);
    int c0 = (lane & 7) * 16;
    const float4* rp = (const float4*)(z + (long long)(r0 + row) * CZ_ + c0);
    float4 v0 = rp[0], v1 = rp[1], v2 = rp[2], v3 = rp[3];
    float s = v0.x + v0.y + v0.z + v0.w + v1.x + v1.y + v1.z + v1.w
            + v2.x + v2.y + v2.z + v2.w + v3.x + v3.y + v3.z + v3.w;
    s += __shfl_xor(s, 1, 64); s += __shfl_xor(s, 2, 64); s += __shfl_xor(s, 4, 64);
    float mu = s * (1.f / CZ_);
    float d[16] = {v0.x - mu, v0.y - mu, v0.z - mu, v0.w - mu,
                   v1.x - mu, v1.y - mu, v1.z - mu, v1.w - mu,
                   v2.x - mu, v2.y - mu, v2.z - mu, v2.w - mu,
                   v3.x - mu, v3.y - mu, v3.z - mu, v3.w - mu};
    float s2 = 0.f;
    #pragma unroll
    for(int i = 0; i < 16; i++) s2 += d[i] * d[i];
    s2 += __shfl_xor(s2, 1, 64); s2 += __shfl_xor(s2, 2, 64); s2 += __shfl_xor(s2, 4, 64);
    float rstd = rsqrtf(s2 * (1.f / CZ_) + 1e-5f);
    const float4* wp = (const float4*)(lnw + c0);
    const float4* bp = (const float4*)(lnb + c0);
    float x[16];
    #pragma unroll
    for(int i = 0; i < 4; i++){
      float4 w4 = wp[i], b4 = bp[i];
      x[i * 4 + 0] = d[i * 4 + 0] * rstd * w4.x + b4.x;
      x[i * 4 + 1] = d[i * 4 + 1] * rstd * w4.y + b4.y;
      x[i * 4 + 2] = d[i * 4 + 2] * rstd * w4.z + b4.z;
      x[i * 4 + 3] = d[i * 4 + 3] * rstd * w4.w + b4.w;
    }
    uint4 p0, p1;
    p0.x = pkbf(x[0], x[1]);  p0.y = pkbf(x[2], x[3]);
    p0.z = pkbf(x[4], x[5]);  p0.w = pkbf(x[6], x[7]);
    p1.x = pkbf(x[8], x[9]);  p1.y = pkbf(x[10], x[11]);
    p1.z = pkbf(x[12], x[13]); p1.w = pkbf(x[14], x[15]);
    *(uint4*)(Xl + ((row * 256 + c0 * 2) ^ ((row & 7) << 4))) = p0;
    *(uint4*)(Xl + ((row * 256 + c0 * 2 + 16) ^ ((row & 7) << 4))) = p1;
  }
  __syncthreads();
  // MFMA projection: waves 0,1 each do a 16-row tile x 4 K-steps
  if(wv < 2){
    f32x4 acc = {0.f, 0.f, 0.f, 0.f};
    #pragma unroll
    for(int ks = 0; ks < 4; ks++){
      int rowA = wv * 16 + l15;
      bf16x8 a = *(const bf16x8*)(Xl + ((rowA * 256 + l4 * 16 + ks * 64) ^ ((rowA & 7) << 4)));
      bf16x8 b = *(const bf16x8*)(Wl + ((l15 * 256 + l4 * 16 + ks * 64) ^ ((l15 & 7) << 4)));
      acc = __builtin_amdgcn_mfma_f32_16x16x32_bf16(a, b, acc, 0, 0, 0);
    }
    if(l15 < 8){
      #pragma unroll
      for(int r = 0; r < 4; r++){
        int rowg = r0 + wv * 16 + l4 * 4 + r;
        int q = rowg >> 8, k = rowg & 255;
        int off = (((l15 * 16 + (q >> 4)) * 16 + (k >> 4)) << 10)
                + ((((q >> 2) & 3) * 16 + (k & 15)) << 2) + (q & 3);
        pb[off] = f2bf(acc[r] * LOG2E);
      }
    }
  }
}

// ---------------- MFMA GEMM 128x128 tile, BK=64, global_load_lds + XOR swizzle ----------------
// RESMODE: 0 none, 1 fp32 residual, 2 bf16 residual.
// OUTMODE: 0 row-major [M][N]; 1 head-major [n>>5][tok=mrow][n&31]; 2 head-major, tok'=(r*128+s).
template<bool HAS_BIAS, bool HAS_SIG, bool RELU, int RESMODE, bool F32OUT, int OUTMODE>
__global__ __launch_bounds__(256) void gemm128(
    const u16* __restrict__ A, const u16* __restrict__ Wt,
    const float* __restrict__ bias, const void* __restrict__ res,
    void* __restrict__ outv, int M, int N, int K, int sigStart){
  __shared__ __attribute__((aligned(16))) unsigned char Ab[16384];
  __shared__ __attribute__((aligned(16))) unsigned char Bb[16384];
  const int t = threadIdx.x;
  const int wv = t >> 6, lane = t & 63, l15 = lane & 15, l4 = lane >> 4;
  const int wm = wv >> 1, wn = wv & 1;
  const unsigned flat = blockIdx.y * gridDim.x + blockIdx.x;
  const unsigned NB = gridDim.x, mper = gridDim.y >> 3;
  const unsigned xcd = flat & 7, j = flat >> 3;
  const unsigned n_blk = j % NB, m_blk = xcd * mper + j / NB;
  const long long m0 = (long long)m_blk * 128;
  const int n0 = n_blk * 128;
  const int srow = t >> 3;
  const int ksw  = ((t & 7) ^ (srow & 7)) * 8;
  const u16* Ag = A  + (m0 + srow) * (long long)K + ksw;
  const u16* Bg = Wt + (long long)(n0 + srow) * K + ksw;
  f32x4 acc[4][4] = {};
  for(int kk = 0; kk < K; kk += 64){
    #pragma unroll
    for(int i = 0; i < 4; i++){
      gl16(Ag + (long long)i * 32 * K + kk, Ab + wv * 1024 + lane * 16 + i * 4096);
      gl16(Bg + (long long)i * 32 * K + kk, Bb + wv * 1024 + lane * 16 + i * 4096);
    }
    asm volatile("s_waitcnt vmcnt(0)" ::: "memory");
    __syncthreads();
    #pragma unroll
    for(int kh = 0; kh < 2; kh++){
      bf16x8 af[4], bq[4];
      #pragma unroll
      for(int mt = 0; mt < 4; mt++){
        int rr = wm * 64 + mt * 16 + l15;
        af[mt] = *(const bf16x8*)(Ab + rr * 128 + ((kh * 64 + l4 * 16) ^ ((rr & 7) << 4)));
      }
      #pragma unroll
      for(int nt = 0; nt < 4; nt++){
        int rr = wn * 64 + nt * 16 + l15;
        bq[nt] = *(const bf16x8*)(Bb + rr * 128 + ((kh * 64 + l4 * 16) ^ ((rr & 7) << 4)));
      }
      #pragma unroll
      for(int mt = 0; mt < 4; mt++)
        #pragma unroll
        for(int nt = 0; nt < 4; nt++)
          acc[mt][nt] = __builtin_amdgcn_mfma_f32_16x16x32_bf16(af[mt], bq[nt], acc[mt][nt], 0, 0, 0);
    }
    __syncthreads();
  }
  float bnt[4]; bool sg[4];
  #pragma unroll
  for(int nt = 0; nt < 4; nt++){
    int ncol = n0 + wn * 64 + nt * 16 + l15;
    bnt[nt] = 0.f; sg[nt] = false;
    if(HAS_BIAS){
      if(HAS_SIG){ sg[nt] = (ncol >= sigStart); bnt[nt] = sg[nt] ? bias[ncol - sigStart] : 0.f; }
      else bnt[nt] = bias[ncol];
    }
  }
  #pragma unroll
  for(int mt = 0; mt < 4; mt++){
    #pragma unroll
    for(int r = 0; r < 4; r++){
      long long mrow = m0 + wm * 64 + mt * 16 + l4 * 4 + r;
      long long tok = mrow;
      if(OUTMODE == 2) tok = (((mrow & 255) << 7) | (mrow >> 8));
      #pragma unroll
      for(int nt = 0; nt < 4; nt++){
        int ncol = n0 + wn * 64 + nt * 16 + l15;
        float v = acc[mt][nt][r] + bnt[nt];
        if(HAS_SIG){ if(sg[nt]) v = 1.f / (1.f + __expf(-v)); }
        if(RELU) v = v > 0.f ? v : 0.f;
        if(RESMODE == 1) v += ((const float*)res)[mrow * N + ncol];
        if(RESMODE == 2) v += bf2f(((const u16*)res)[mrow * N + ncol]);
        long long oidx;
        if(OUTMODE == 0) oidx = mrow * N + ncol;
        else oidx = ((long long)(ncol >> 5) << 20) + tok * 32 + (ncol & 31);
        if(F32OUT) ((float*)outv)[oidx] = v;
        else       ((u16*)outv)[oidx] = f2bf(v);
      }
    }
  }
}

// ---------------- fused attention: head-major contiguous inputs (tstride=32) ----------------
// K+V^T in LDS, exp2 softmax, chunk-permuted P, gated epilogue.
template<int L, bool HAS_BIAS>
__global__ __launch_bounds__(256) void atten_kernel(
    const u16* __restrict__ qg, const u16* __restrict__ kg, const u16* __restrict__ vg,
    const u16* __restrict__ gg, const u16* __restrict__ pb, const float* __restrict__ mask,
    u16* __restrict__ og,
    long long obase_in, long long obase_o, long long ostride,
    long long mbase_mul, int mstride){
  __shared__ __attribute__((aligned(16))) unsigned char smem[L * 128 + 8192];
  unsigned char* Kl = smem;              // [L][32] bf16, XOR swizzle
  unsigned char* Vt = smem + L * 64;     // [32][L] bf16 (V^T, k-permuted), swizzled
  unsigned char* Pl = smem + L * 128;    // per-wave [16][64] bf16 chunk

  const int t = threadIdx.x;
  const int wv = t >> 6, lane = t & 63, l15 = lane & 15, l4 = lane >> 4;
  const int h = blockIdx.x & 7;
  const int outer = blockIdx.x >> 3;
  const long long base  = ((long long)h << 20) + (long long)outer * obase_in;  // elems, head-major
  const long long baseo = (long long)outer * obase_o + h * CA_;
  const long long mb = (long long)outer * mbase_mul;
  const int KT = L / 16, NC = L / 64;

  // stage K: [L][32] swizzled; source contiguous (L*64 bytes)
  #pragma unroll
  for(int j = 0; j < L * 4; j += 256){
    int cid = j + t;
    int row = cid >> 2, ko = cid & 3;
    int4 kv = *(const int4*)(kg + base + row * 32 + ko * 8);
    *(int4*)(Kl + ((row * 64 + ko * 16) ^ ((row & 7) << 4))) = kv;
  }
  // stage V transposed (k-permuted); source contiguous
  if(t < L){
    __attribute__((aligned(16))) u16 tmp[32];
    const u16* vp = vg + base + t * 32;
    #pragma unroll
    for(int j2 = 0; j2 < 4; j2++) ((int4*)tmp)[j2] = *(const int4*)(vp + j2 * 8);
    int kp = (t >> 6) * 64 + (t & 15) * 4 + ((t >> 4) & 3);   // permuted key index
    #pragma unroll
    for(int c = 0; c < 32; c++)
      *(u16*)(Vt + (((c * L + kp) * 2) ^ ((c & 7) << 4))) = tmp[c];
  }
  __syncthreads();

  float mskb[L / 16];
  #pragma unroll
  for(int kt = 0; kt < KT; kt++)
    mskb[kt] = (mask[mb + (long long)(kt * 16 + l15) * mstride] - 1.f) * (1e9f * LOG2E);

  unsigned char* Pw = Pl + wv * 2048;
  const int NQ = L / 4;
  #pragma unroll
  for(int qt = 0; qt < NQ / 16; qt++){
    const int qrow0 = wv * NQ + qt * 16;
    bf16x8 aq = *(const bf16x8*)(qg + base + (qrow0 + l15) * 32 + l4 * 8);
    f32x4 lac[L / 16];
    #pragma unroll
    for(int kt = 0; kt < KT; kt++){
      int kr = kt * 16 + l15;
      bf16x8 bk = *(const bf16x8*)(Kl + ((kr * 64 + l4 * 16) ^ ((kr & 7) << 4)));
      f32x4 zz = {0.f, 0.f, 0.f, 0.f};
      lac[kt] = __builtin_amdgcn_mfma_f32_16x16x32_bf16(aq, bk, zz, 0, 0, 0);
    }
    // merged bias + mask + exp2 + sum (log2e folded into q-scale/bias/mask)
    const u16* tile = HAS_BIAS ? (pb + (((h * 16 + (qrow0 >> 4)) * 16) << 10) + lane * 4) : nullptr;
    float sm[4] = {1e-30f, 1e-30f, 1e-30f, 1e-30f};
    #pragma unroll
    for(int kt = 0; kt < KT; kt++){
      float mm = mskb[kt];
      if(HAS_BIAS){
        ushort4 b4 = *(const ushort4*)(tile + (kt << 10));
        lac[kt][0] = fexp2(lac[kt][0] + mm + bf2f(b4.x));
        lac[kt][1] = fexp2(lac[kt][1] + mm + bf2f(b4.y));
        lac[kt][2] = fexp2(lac[kt][2] + mm + bf2f(b4.z));
        lac[kt][3] = fexp2(lac[kt][3] + mm + bf2f(b4.w));
      } else {
        #pragma unroll
        for(int r = 0; r < 4; r++) lac[kt][r] = fexp2(lac[kt][r] + mm);
      }
      #pragma unroll
      for(int r = 0; r < 4; r++) sm[r] += lac[kt][r];
    }
    #pragma unroll
    for(int mo = 1; mo < 16; mo <<= 1)
      #pragma unroll
      for(int r = 0; r < 4; r++) sm[r] += __shfl_xor(sm[r], mo, 64);
    float inv[4];
    #pragma unroll
    for(int r = 0; r < 4; r++) inv[r] = 1.f / sm[r];
    // chunked PV on unnormalized P; lane's 4 chunk-values contiguous at col l15*4
    f32x4 oac[2] = {{0,0,0,0},{0,0,0,0}};
    #pragma unroll
    for(int ch = 0; ch < NC; ch++){
      asm volatile("" ::: "memory");
      #pragma unroll
      for(int r = 0; r < 4; r++){
        int qp = l4 * 4 + r;
        uint2 pk2;
        pk2.x = pkbf(lac[ch * 4 + 0][r], lac[ch * 4 + 1][r]);
        pk2.y = pkbf(lac[ch * 4 + 2][r], lac[ch * 4 + 3][r]);
        *(uint2*)(Pw + qp * 128 + ((l15 * 8) ^ ((qp & 7) << 4))) = pk2;
      }
      asm volatile("s_waitcnt lgkmcnt(0)" ::: "memory");
      #pragma unroll
      for(int ksl = 0; ksl < 2; ksl++){
        bf16x8 ap = *(const bf16x8*)(Pw + l15 * 128 + ((ksl * 64 + l4 * 16) ^ ((l15 & 7) << 4)));
        #pragma unroll
        for(int ct = 0; ct < 2; ct++){
          int c = ct * 16 + l15;
          bf16x8 bv = *(const bf16x8*)(Vt + (((c * L + ch * 64 + ksl * 32 + l4 * 8) * 2) ^ ((c & 7) << 4)));
          oac[ct] = __builtin_amdgcn_mfma_f32_16x16x32_bf16(ap, bv, oac[ct], 0, 0, 0);
        }
      }
    }
    // epilogue: normalize, multiply sigmoid-gate (contiguous), store to standard layout
    #pragma unroll
    for(int ct = 0; ct < 2; ct++)
      #pragma unroll
      for(int r = 0; r < 4; r++){
        int qi = qrow0 + l4 * 4 + r, c = ct * 16 + l15;
        float g = bf2f(gg[base + qi * 32 + c]);
        og[baseo + (long long)qi * ostride + c] = f2bf(oac[ct][r] * inv[r] * g);
      }
  }
}

extern "C" void kernel_launch(void* const* d_in, const int* in_sizes, int n_in,
                              void* d_out, int out_size, void* d_ws, size_t ws_size,
                              hipStream_t stream){
  const float* m        = (const float*)d_in[0];
  const float* m_mask   = (const float*)d_in[1];
  const float* z        = (const float*)d_in[2];
  const float* row_ln_w = (const float*)d_in[3];
  const float* row_ln_b = (const float*)d_in[4];
  const float* row_z_ln_w = (const float*)d_in[5];
  const float* row_z_ln_b = (const float*)d_in[6];
  const float* row_bg   = (const float*)d_in[12];
  const float* row_bo   = (const float*)d_in[14];
  const float* col_ln_w = (const float*)d_in[15];
  const float* col_ln_b = (const float*)d_in[16];
  const float* col_bg   = (const float*)d_in[21];
  const float* col_bo   = (const float*)d_in[23];
  const float* tr_ln_w  = (const float*)d_in[24];
  const float* tr_ln_b  = (const float*)d_in[25];
  const float* tr_b1    = (const float*)d_in[27];
  const float* tr_b2    = (const float*)d_in[29];
  float* out = (float*)d_out;
  char* ws = (char*)d_ws;

  // buffer plan (bf16 residual stream):
  //  bx  [32768][256]: ln1-out -> m1 (bf16) -> ln3-out
  //  fq  32 sections of [32768][32] (head-major QKVG); later fq[0..8.4M)=m2, fq+8.4M..=h1
  //  t_o [32768][256]: atten1-out -> ln2-out -> atten2-out
  u16* bx  = (u16*)ws;
  u16* fq  = bx + 8388608;
  u16* t_o = fq + 33554432;
  u16* pb  = t_o + 8388608;               // permuted pair bias, 2M bf16
  u16* wt  = pb + 2097152;                // transposed weights
  u16* m2  = fq;                          // [32768][256] bf16 (after col QKVG consumed)
  u16* h1  = fq + 8388608;                // [32768][1024] bf16

  const long long HSEC = 1ll << 20;       // 32768*32 elems per head-section

  WSrc srcs;
  srcs.p[0] = (const float*)d_in[7];   // row_wq
  srcs.p[1] = (const float*)d_in[8];   // row_wk
  srcs.p[2] = (const float*)d_in[9];   // row_wv
  srcs.p[3] = (const float*)d_in[11];  // row_wg
  srcs.p[4] = (const float*)d_in[13];  // row_wo
  srcs.p[5] = (const float*)d_in[17];  // col_wq
  srcs.p[6] = (const float*)d_in[18];  // col_wk
  srcs.p[7] = (const float*)d_in[19];  // col_wv
  srcs.p[8] = (const float*)d_in[20];  // col_wg
  srcs.p[9] = (const float*)d_in[22];  // col_wo
  srcs.p[10] = (const float*)d_in[26]; // tr_w1
  srcs.p[11] = (const float*)d_in[28]; // tr_w2

  dim3 b256(256);
  transpose_all<<<dim3(4608), b256, 0, stream>>>(srcs, wt);
  pair_bias_kernel<<<dim3(2048), b256, 0, stream>>>(z, row_z_ln_w, row_z_ln_b,
                                                    (const float*)d_in[10], pb);

  // ---- row attention ----
  ln_kernel<false><<<dim3(8192), b256, 0, stream>>>(m, row_ln_w, row_ln_b, bx);
  gemm128<true,true,false,0,false,1><<<dim3(8,256), b256, 0, stream>>>(
      bx, wt, row_bg, nullptr, fq, 32768, 1024, 256, 768);
  // row: token = s*256 + q; base per outer(s) = s*256*32 = s*8192
  atten_kernel<256,true><<<dim3(1024), b256, 0, stream>>>(
      fq, fq + 8 * HSEC, fq + 16 * HSEC, fq + 24 * HSEC, pb, m_mask, t_o,
      8192, 65536, 256, 256, 1);
  gemm128<true,false,false,1,false,0><<<dim3(2,256), b256, 0, stream>>>(
      t_o, wt + 262144, row_bo, m, bx, 32768, 256, 256, 0);   // m1 -> bx (bf16)

  // ---- column attention ----
  ln_kernel<true><<<dim3(8192), b256, 0, stream>>>(bx, col_ln_w, col_ln_b, t_o);
  gemm128<true,true,false,0,false,2><<<dim3(8,256), b256, 0, stream>>>(
      t_o, wt + 327680, col_bg, nullptr, fq, 32768, 1024, 256, 768);
  // col: token' = r*128 + s; base per outer(r) = r*128*32 = r*4096; output row = s*256 + r
  atten_kernel<128,false><<<dim3(2048), b256, 0, stream>>>(
      fq, fq + 8 * HSEC, fq + 16 * HSEC, fq + 24 * HSEC, nullptr, m_mask, t_o,
      4096, 256, 65536, 1, 256);
  gemm128<true,false,false,2,false,0><<<dim3(2,256), b256, 0, stream>>>(
      t_o, wt + 589824, col_bo, bx, m2, 32768, 256, 256, 0);  // m2 -> fq[0..] (bf16)

  // ---- transition ----
  ln_kernel<true><<<dim3(8192), b256, 0, stream>>>(m2, tr_ln_w, tr_ln_b, bx);
  gemm128<true,false,true,0,false,0><<<dim3(8,256), b256, 0, stream>>>(
      bx, wt + 655360, tr_b1, nullptr, h1, 32768, 1024, 256, 0);
  gemm128<true,false,false,2,true,0><<<dim3(2,256), b256, 0, stream>>>(
      h1, wt + 917504, tr_b2, m2, out, 32768, 256, 1024, 0);
}

// Round 11
// 262.319 us; speedup vs baseline: 1.0809x; 1.0224x over previous
//
#include <hip/hip_runtime.h>
#include <stdint.h>

#define S_ 128
#define R_ 256
#define CM_ 256
#define H_ 8
#define CA_ 32
#define CZ_ 128

typedef unsigned short u16;
typedef __bf16 bf16x8 __attribute__((ext_vector_type(8)));
typedef float f32x4 __attribute__((ext_vector_type(4)));

#define LOG2E 1.4426950408889634f

__device__ __forceinline__ float bf2f(u16 u){ unsigned v = ((unsigned)u) << 16; float f; __builtin_memcpy(&f, &v, 4); return f; }
__device__ __forceinline__ u16 f2bf(float f){ __bf16 h = (__bf16)f; u16 u; __builtin_memcpy(&u, &h, 2); return u; }
__device__ __forceinline__ unsigned pkbf(float lo, float hi){
  unsigned r; asm("v_cvt_pk_bf16_f32 %0, %1, %2" : "=v"(r) : "v"(lo), "v"(hi)); return r;
}
__device__ __forceinline__ float fexp2(float x){
  float r; asm("v_exp_f32 %0, %1" : "=v"(r) : "v"(x)); return r;
}

__device__ __forceinline__ void gl16(const void* g, void* l){
  __builtin_amdgcn_global_load_lds((const __attribute__((address_space(1))) void*)g,
                                   (__attribute__((address_space(3))) void*)l, 16, 0, 0);
}

// ---------------- all 12 weight transposes in one launch ----------------
struct WSrc { const float* p[12]; };
__global__ __launch_bounds__(256) void transpose_all(WSrc srcs, u16* __restrict__ dst){
  int b = blockIdx.x, t = threadIdx.x;
  int job, idx;
  if(b < 2560){ job = b >> 8; idx = ((b & 255) << 8) + t; }
  else if(b < 3584){ job = 10; idx = ((b - 2560) << 8) + t; }
  else { job = 11; idx = ((b - 3584) << 8) + t; }
  int K = (job == 11) ? 1024 : 256;
  int N = (job == 10) ? 1024 : 256;
  int off;
  if(job < 10) off = job * 65536;
  else if(job == 10) off = 655360;
  else off = 917504;
  int k = idx / N, n = idx - k * N;
  // fold CA^-0.5 * log2(e) into wq so softmax can use exp2 directly
  float sc = (job == 0 || job == 5) ? (0.17677669529663687f * LOG2E) : 1.f;
  dst[off + n * K + k] = f2bf(srcs.p[job][idx] * sc);
}

// ---------------- LayerNorm over last dim 256 -> bf16 out; input fp32 or bf16 ----------------
template<bool BF16IN>
__global__ __launch_bounds__(256) void ln_kernel(const void* __restrict__ inv, const float* __restrict__ w,
                          const float* __restrict__ b, u16* __restrict__ out){
  int wv = threadIdx.x >> 6, lane = threadIdx.x & 63;
  long long row = (long long)blockIdx.x * 4 + wv;
  float vx, vy, vz, vw;
  if(BF16IN){
    ushort4 v4 = ((const ushort4*)((const u16*)inv + row * CM_))[lane];
    vx = bf2f(v4.x); vy = bf2f(v4.y); vz = bf2f(v4.z); vw = bf2f(v4.w);
  } else {
    float4 v4 = ((const float4*)((const float*)inv + row * CM_))[lane];
    vx = v4.x; vy = v4.y; vz = v4.z; vw = v4.w;
  }
  float s = vx + vy + vz + vw;
  for(int mo = 32; mo; mo >>= 1) s += __shfl_xor(s, mo, 64);
  float mu = s * (1.f / CM_);
  float dx = vx - mu, dy = vy - mu, dz = vz - mu, dw = vw - mu;
  float s2 = dx * dx + dy * dy + dz * dz + dw * dw;
  for(int mo = 32; mo; mo >>= 1) s2 += __shfl_xor(s2, mo, 64);
  float rstd = rsqrtf(s2 * (1.f / CM_) + 1e-5f);
  float4 w4 = ((const float4*)w)[lane];
  float4 b4 = ((const float4*)b)[lane];
  ushort4 st;
  st.x = f2bf(dx * rstd * w4.x + b4.x);
  st.y = f2bf(dy * rstd * w4.y + b4.y);
  st.z = f2bf(dz * rstd * w4.z + b4.z);
  st.w = f2bf(dw * rstd * w4.w + b4.w);
  *(ushort4*)(out + row * CM_ + lane * 4) = st;
}

// ---------------- pair bias v2: LN(z) -> LDS -> MFMA @ wb -> permuted bf16 (x log2e) ------
__global__ __launch_bounds__(256) void pair_bias_kernel(const float* __restrict__ z, const float* __restrict__ lnw,
                                 const float* __restrict__ lnb, const float* __restrict__ wb,
                                 u16* __restrict__ pb){
  __shared__ __attribute__((aligned(16))) unsigned char Xl[32 * 256];  // [32][128] bf16, XOR swz
  __shared__ __attribute__((aligned(16))) unsigned char Wl[16 * 256];  // [16 n][128 k] bf16, XOR swz
  const int t = threadIdx.x;
  const int wv = t >> 6, lane = t & 63, l15 = lane & 15, l4 = lane >> 4;
  const int r0 = blockIdx.x * 32;

  // stage wb -> Wl (transposed [n][k], heads 8..15 zero-padded)
  if(t < 128){
    const float4* wr = (const float4*)(wb + t * 8);
    float4 a = wr[0], bq = wr[1];
    u16 vals[8] = {f2bf(a.x), f2bf(a.y), f2bf(a.z), f2bf(a.w),
                   f2bf(bq.x), f2bf(bq.y), f2bf(bq.z), f2bf(bq.w)};
    #pragma unroll
    for(int n = 0; n < 8; n++){
      *(u16*)(Wl + ((n * 256 + t * 2) ^ ((n & 7) << 4))) = vals[n];
      *(u16*)(Wl + (((n + 8) * 256 + t * 2) ^ ((n & 7) << 4))) = 0;
    }
  }
  // LN: row = wv*8 + (lane>>3), 16 c per lane
  {
    int row = wv * 8 + (lane >> 3);
    int c0 = (lane & 7) * 16;
    const float4* rp = (const float4*)(z + (long long)(r0 + row) * CZ_ + c0);
    float4 v0 = rp[0], v1 = rp[1], v2 = rp[2], v3 = rp[3];
    float s = v0.x + v0.y + v0.z + v0.w + v1.x + v1.y + v1.z + v1.w
            + v2.x + v2.y + v2.z + v2.w + v3.x + v3.y + v3.z + v3.w;
    s += __shfl_xor(s, 1, 64); s += __shfl_xor(s, 2, 64); s += __shfl_xor(s, 4, 64);
    float mu = s * (1.f / CZ_);
    float d[16] = {v0.x - mu, v0.y - mu, v0.z - mu, v0.w - mu,
                   v1.x - mu, v1.y - mu, v1.z - mu, v1.w - mu,
                   v2.x - mu, v2.y - mu, v2.z - mu, v2.w - mu,
                   v3.x - mu, v3.y - mu, v3.z - mu, v3.w - mu};
    float s2 = 0.f;
    #pragma unroll
    for(int i = 0; i < 16; i++) s2 += d[i] * d[i];
    s2 += __shfl_xor(s2, 1, 64); s2 += __shfl_xor(s2, 2, 64); s2 += __shfl_xor(s2, 4, 64);
    float rstd = rsqrtf(s2 * (1.f / CZ_) + 1e-5f);
    const float4* wp = (const float4*)(lnw + c0);
    const float4* bp = (const float4*)(lnb + c0);
    float x[16];
    #pragma unroll
    for(int i = 0; i < 4; i++){
      float4 w4 = wp[i], b4 = bp[i];
      x[i * 4 + 0] = d[i * 4 + 0] * rstd * w4.x + b4.x;
      x[i * 4 + 1] = d[i * 4 + 1] * rstd * w4.y + b4.y;
      x[i * 4 + 2] = d[i * 4 + 2] * rstd * w4.z + b4.z;
      x[i * 4 + 3] = d[i * 4 + 3] * rstd * w4.w + b4.w;
    }
    uint4 p0, p1;
    p0.x = pkbf(x[0], x[1]);  p0.y = pkbf(x[2], x[3]);
    p0.z = pkbf(x[4], x[5]);  p0.w = pkbf(x[6], x[7]);
    p1.x = pkbf(x[8], x[9]);  p1.y = pkbf(x[10], x[11]);
    p1.z = pkbf(x[12], x[13]); p1.w = pkbf(x[14], x[15]);
    *(uint4*)(Xl + ((row * 256 + c0 * 2) ^ ((row & 7) << 4))) = p0;
    *(uint4*)(Xl + ((row * 256 + c0 * 2 + 16) ^ ((row & 7) << 4))) = p1;
  }
  __syncthreads();
  // MFMA projection: waves 0,1 each do a 16-row tile x 4 K-steps
  if(wv < 2){
    f32x4 acc = {0.f, 0.f, 0.f, 0.f};
    #pragma unroll
    for(int ks = 0; ks < 4; ks++){
      int rowA = wv * 16 + l15;
      bf16x8 a = *(const bf16x8*)(Xl + ((rowA * 256 + l4 * 16 + ks * 64) ^ ((rowA & 7) << 4)));
      bf16x8 b = *(const bf16x8*)(Wl + ((l15 * 256 + l4 * 16 + ks * 64) ^ ((l15 & 7) << 4)));
      acc = __builtin_amdgcn_mfma_f32_16x16x32_bf16(a, b, acc, 0, 0, 0);
    }
    if(l15 < 8){
      #pragma unroll
      for(int r = 0; r < 4; r++){
        int rowg = r0 + wv * 16 + l4 * 4 + r;
        int q = rowg >> 8, k = rowg & 255;
        int off = (((l15 * 16 + (q >> 4)) * 16 + (k >> 4)) << 10)
                + ((((q >> 2) & 3) * 16 + (k & 15)) << 2) + (q & 3);
        pb[off] = f2bf(acc[r] * LOG2E);
      }
    }
  }
}

// ---------------- MFMA GEMM 128x128 tile, BK=64, global_load_lds + XOR swizzle ----------------
// RESMODE: 0 none, 1 fp32 residual, 2 bf16 residual.
// OUTMODE: 0 row-major [M][N]; 1 head-major [n>>5][tok=mrow][n&31]; 2 head-major, tok'=(r*128+s).
template<bool HAS_BIAS, bool HAS_SIG, bool RELU, int RESMODE, bool F32OUT, int OUTMODE>
__global__ __launch_bounds__(256) void gemm128(
    const u16* __restrict__ A, const u16* __restrict__ Wt,
    const float* __restrict__ bias, const void* __restrict__ res,
    void* __restrict__ outv, int M, int N, int K, int sigStart){
  __shared__ __attribute__((aligned(16))) unsigned char Ab[16384];
  __shared__ __attribute__((aligned(16))) unsigned char Bb[16384];
  const int t = threadIdx.x;
  const int wv = t >> 6, lane = t & 63, l15 = lane & 15, l4 = lane >> 4;
  const int wm = wv >> 1, wn = wv & 1;
  const unsigned flat = blockIdx.y * gridDim.x + blockIdx.x;
  const unsigned NB = gridDim.x, mper = gridDim.y >> 3;
  const unsigned xcd = flat & 7, j = flat >> 3;
  const unsigned n_blk = j % NB, m_blk = xcd * mper + j / NB;
  const long long m0 = (long long)m_blk * 128;
  const int n0 = n_blk * 128;
  const int srow = t >> 3;
  const int ksw  = ((t & 7) ^ (srow & 7)) * 8;
  const u16* Ag = A  + (m0 + srow) * (long long)K + ksw;
  const u16* Bg = Wt + (long long)(n0 + srow) * K + ksw;
  f32x4 acc[4][4] = {};
  for(int kk = 0; kk < K; kk += 64){
    #pragma unroll
    for(int i = 0; i < 4; i++){
      gl16(Ag + (long long)i * 32 * K + kk, Ab + wv * 1024 + lane * 16 + i * 4096);
      gl16(Bg + (long long)i * 32 * K + kk, Bb + wv * 1024 + lane * 16 + i * 4096);
    }
    asm volatile("s_waitcnt vmcnt(0)" ::: "memory");
    __syncthreads();
    #pragma unroll
    for(int kh = 0; kh < 2; kh++){
      bf16x8 af[4], bq[4];
      #pragma unroll
      for(int mt = 0; mt < 4; mt++){
        int rr = wm * 64 + mt * 16 + l15;
        af[mt] = *(const bf16x8*)(Ab + rr * 128 + ((kh * 64 + l4 * 16) ^ ((rr & 7) << 4)));
      }
      #pragma unroll
      for(int nt = 0; nt < 4; nt++){
        int rr = wn * 64 + nt * 16 + l15;
        bq[nt] = *(const bf16x8*)(Bb + rr * 128 + ((kh * 64 + l4 * 16) ^ ((rr & 7) << 4)));
      }
      #pragma unroll
      for(int mt = 0; mt < 4; mt++)
        #pragma unroll
        for(int nt = 0; nt < 4; nt++)
          acc[mt][nt] = __builtin_amdgcn_mfma_f32_16x16x32_bf16(af[mt], bq[nt], acc[mt][nt], 0, 0, 0);
    }
    __syncthreads();
  }
  float bnt[4]; bool sg[4];
  #pragma unroll
  for(int nt = 0; nt < 4; nt++){
    int ncol = n0 + wn * 64 + nt * 16 + l15;
    bnt[nt] = 0.f; sg[nt] = false;
    if(HAS_BIAS){
      if(HAS_SIG){ sg[nt] = (ncol >= sigStart); bnt[nt] = sg[nt] ? bias[ncol - sigStart] : 0.f; }
      else bnt[nt] = bias[ncol];
    }
  }
  #pragma unroll
  for(int mt = 0; mt < 4; mt++){
    #pragma unroll
    for(int r = 0; r < 4; r++){
      long long mrow = m0 + wm * 64 + mt * 16 + l4 * 4 + r;
      long long tok = mrow;
      if(OUTMODE == 2) tok = (((mrow & 255) << 7) | (mrow >> 8));
      #pragma unroll
      for(int nt = 0; nt < 4; nt++){
        int ncol = n0 + wn * 64 + nt * 16 + l15;
        float v = acc[mt][nt][r] + bnt[nt];
        if(HAS_SIG){ if(sg[nt]) v = 1.f / (1.f + __expf(-v)); }
        if(RELU) v = v > 0.f ? v : 0.f;
        if(RESMODE == 1) v += ((const float*)res)[mrow * N + ncol];
        if(RESMODE == 2) v += bf2f(((const u16*)res)[mrow * N + ncol]);
        long long oidx;
        if(OUTMODE == 0) oidx = mrow * N + ncol;
        else oidx = ((long long)(ncol >> 5) << 20) + tok * 32 + (ncol & 31);
        if(F32OUT) ((float*)outv)[oidx] = v;
        else       ((u16*)outv)[oidx] = f2bf(v);
      }
    }
  }
}

// ---------------- fused attention: head-major contiguous inputs (tstride=32) ----------------
// K+V^T in LDS, exp2 softmax, chunk-permuted P, row-sum via ones-MFMA (no shfl), gated epilogue.
template<int L, bool HAS_BIAS>
__global__ __launch_bounds__(256) void atten_kernel(
    const u16* __restrict__ qg, const u16* __restrict__ kg, const u16* __restrict__ vg,
    const u16* __restrict__ gg, const u16* __restrict__ pb, const float* __restrict__ mask,
    u16* __restrict__ og,
    long long obase_in, long long obase_o, long long ostride,
    long long mbase_mul, int mstride){
  __shared__ __attribute__((aligned(16))) unsigned char smem[L * 128 + 8192];
  unsigned char* Kl = smem;              // [L][32] bf16, XOR swizzle
  unsigned char* Vt = smem + L * 64;     // [32][L] bf16 (V^T, k-permuted), swizzled
  unsigned char* Pl = smem + L * 128;    // per-wave [16][64] bf16 chunk

  const int t = threadIdx.x;
  const int wv = t >> 6, lane = t & 63, l15 = lane & 15, l4 = lane >> 4;
  const int h = blockIdx.x & 7;
  const int outer = blockIdx.x >> 3;
  const long long base  = ((long long)h << 20) + (long long)outer * obase_in;  // elems, head-major
  const long long baseo = (long long)outer * obase_o + h * CA_;
  const long long mb = (long long)outer * mbase_mul;
  const int KT = L / 16, NC = L / 64;

  // stage K: [L][32] swizzled; source contiguous (L*64 bytes)
  #pragma unroll
  for(int j = 0; j < L * 4; j += 256){
    int cid = j + t;
    int row = cid >> 2, ko = cid & 3;
    int4 kv = *(const int4*)(kg + base + row * 32 + ko * 8);
    *(int4*)(Kl + ((row * 64 + ko * 16) ^ ((row & 7) << 4))) = kv;
  }
  // stage V transposed (k-permuted); source contiguous. TPT threads per token.
  {
    const int TPT = 256 / L;                 // 1 (L=256) or 2 (L=128)
    const int CPT = 32 / TPT;                // cols per thread
    int tok = t / TPT, part = t - tok * TPT;
    int c0 = part * CPT;
    __attribute__((aligned(16))) u16 tmp[32];
    const u16* vp = vg + base + tok * 32 + c0;
    #pragma unroll
    for(int j2 = 0; j2 < CPT / 8; j2++) ((int4*)tmp)[j2] = *(const int4*)(vp + j2 * 8);
    int kp = (tok >> 6) * 64 + (tok & 15) * 4 + ((tok >> 4) & 3);   // permuted key index
    #pragma unroll
    for(int ci = 0; ci < CPT; ci++){
      int c = c0 + ci;
      *(u16*)(Vt + (((c * L + kp) * 2) ^ ((c & 7) << 4))) = tmp[ci];
    }
  }
  __syncthreads();

  float mskb[L / 16];
  #pragma unroll
  for(int kt = 0; kt < KT; kt++)
    mskb[kt] = (mask[mb + (long long)(kt * 16 + l15) * mstride] - 1.f) * (1e9f * LOG2E);

  // all-ones B fragment for row-sum MFMA
  bf16x8 ones;
  #pragma unroll
  for(int j = 0; j < 8; j++) ones[j] = (__bf16)1.0f;

  unsigned char* Pw = Pl + wv * 2048;
  const int NQ = L / 4;
  #pragma unroll
  for(int qt = 0; qt < NQ / 16; qt++){
    const int qrow0 = wv * NQ + qt * 16;
    bf16x8 aq = *(const bf16x8*)(qg + base + (qrow0 + l15) * 32 + l4 * 8);
    f32x4 lac[L / 16];
    #pragma unroll
    for(int kt = 0; kt < KT; kt++){
      int kr = kt * 16 + l15;
      bf16x8 bk = *(const bf16x8*)(Kl + ((kr * 64 + l4 * 16) ^ ((kr & 7) << 4)));
      f32x4 zz = {0.f, 0.f, 0.f, 0.f};
      lac[kt] = __builtin_amdgcn_mfma_f32_16x16x32_bf16(aq, bk, zz, 0, 0, 0);
    }
    // merged bias + mask + exp2 (log2e folded into q-scale/bias/mask); sum comes from ones-MFMA
    const u16* tile = HAS_BIAS ? (pb + (((h * 16 + (qrow0 >> 4)) * 16) << 10) + lane * 4) : nullptr;
    #pragma unroll
    for(int kt = 0; kt < KT; kt++){
      float mm = mskb[kt];
      if(HAS_BIAS){
        ushort4 b4 = *(const ushort4*)(tile + (kt << 10));
        lac[kt][0] = fexp2(lac[kt][0] + mm + bf2f(b4.x));
        lac[kt][1] = fexp2(lac[kt][1] + mm + bf2f(b4.y));
        lac[kt][2] = fexp2(lac[kt][2] + mm + bf2f(b4.z));
        lac[kt][3] = fexp2(lac[kt][3] + mm + bf2f(b4.w));
      } else {
        #pragma unroll
        for(int r = 0; r < 4; r++) lac[kt][r] = fexp2(lac[kt][r] + mm);
      }
    }
    // chunked PV on unnormalized P; row-sum accumulated via mfma(P, ones)
    f32x4 oac[2] = {{0,0,0,0},{0,0,0,0}};
    f32x4 osum = {0.f, 0.f, 0.f, 0.f};
    #pragma unroll
    for(int ch = 0; ch < NC; ch++){
      asm volatile("" ::: "memory");
      #pragma unroll
      for(int r = 0; r < 4; r++){
        int qp = l4 * 4 + r;
        uint2 pk2;
        pk2.x = pkbf(lac[ch * 4 + 0][r], lac[ch * 4 + 1][r]);
        pk2.y = pkbf(lac[ch * 4 + 2][r], lac[ch * 4 + 3][r]);
        *(uint2*)(Pw + qp * 128 + ((l15 * 8) ^ ((qp & 7) << 4))) = pk2;
      }
      asm volatile("s_waitcnt lgkmcnt(0)" ::: "memory");
      #pragma unroll
      for(int ksl = 0; ksl < 2; ksl++){
        bf16x8 ap = *(const bf16x8*)(Pw + l15 * 128 + ((ksl * 64 + l4 * 16) ^ ((l15 & 7) << 4)));
        osum = __builtin_amdgcn_mfma_f32_16x16x32_bf16(ap, ones, osum, 0, 0, 0);
        #pragma unroll
        for(int ct = 0; ct < 2; ct++){
          int c = ct * 16 + l15;
          bf16x8 bv = *(const bf16x8*)(Vt + (((c * L + ch * 64 + ksl * 32 + l4 * 8) * 2) ^ ((c & 7) << 4)));
          oac[ct] = __builtin_amdgcn_mfma_f32_16x16x32_bf16(ap, bv, oac[ct], 0, 0, 0);
        }
      }
    }
    float inv[4];
    #pragma unroll
    for(int r = 0; r < 4; r++) inv[r] = 1.f / (osum[r] + 1e-30f);
    // epilogue: normalize, multiply sigmoid-gate (contiguous), store to standard layout
    #pragma unroll
    for(int ct = 0; ct < 2; ct++)
      #pragma unroll
      for(int r = 0; r < 4; r++){
        int qi = qrow0 + l4 * 4 + r, c = ct * 16 + l15;
        float g = bf2f(gg[base + qi * 32 + c]);
        og[baseo + (long long)qi * ostride + c] = f2bf(oac[ct][r] * inv[r] * g);
      }
  }
}

extern "C" void kernel_launch(void* const* d_in, const int* in_sizes, int n_in,
                              void* d_out, int out_size, void* d_ws, size_t ws_size,
                              hipStream_t stream){
  const float* m        = (const float*)d_in[0];
  const float* m_mask   = (const float*)d_in[1];
  const float* z        = (const float*)d_in[2];
  const float* row_ln_w = (const float*)d_in[3];
  const float* row_ln_b = (const float*)d_in[4];
  const float* row_z_ln_w = (const float*)d_in[5];
  const float* row_z_ln_b = (const float*)d_in[6];
  const float* row_bg   = (const float*)d_in[12];
  const float* row_bo   = (const float*)d_in[14];
  const float* col_ln_w = (const float*)d_in[15];
  const float* col_ln_b = (const float*)d_in[16];
  const float* col_bg   = (const float*)d_in[21];
  const float* col_bo   = (const float*)d_in[23];
  const float* tr_ln_w  = (const float*)d_in[24];
  const float* tr_ln_b  = (const float*)d_in[25];
  const float* tr_b1    = (const float*)d_in[27];
  const float* tr_b2    = (const float*)d_in[29];
  float* out = (float*)d_out;
  char* ws = (char*)d_ws;

  // buffer plan (bf16 residual stream):
  //  bx  [32768][256]: ln1-out -> m1 (bf16) -> ln3-out
  //  fq  32 sections of [32768][32] (head-major QKVG); later fq[0..8.4M)=m2, fq+8.4M..=h1
  //  t_o [32768][256]: atten1-out -> ln2-out -> atten2-out
  u16* bx  = (u16*)ws;
  u16* fq  = bx + 8388608;
  u16* t_o = fq + 33554432;
  u16* pb  = t_o + 8388608;               // permuted pair bias, 2M bf16
  u16* wt  = pb + 2097152;                // transposed weights
  u16* m2  = fq;                          // [32768][256] bf16 (after col QKVG consumed)
  u16* h1  = fq + 8388608;                // [32768][1024] bf16

  const long long HSEC = 1ll << 20;       // 32768*32 elems per head-section

  WSrc srcs;
  srcs.p[0] = (const float*)d_in[7];   // row_wq
  srcs.p[1] = (const float*)d_in[8];   // row_wk
  srcs.p[2] = (const float*)d_in[9];   // row_wv
  srcs.p[3] = (const float*)d_in[11];  // row_wg
  srcs.p[4] = (const float*)d_in[13];  // row_wo
  srcs.p[5] = (const float*)d_in[17];  // col_wq
  srcs.p[6] = (const float*)d_in[18];  // col_wk
  srcs.p[7] = (const float*)d_in[19];  // col_wv
  srcs.p[8] = (const float*)d_in[20];  // col_wg
  srcs.p[9] = (const float*)d_in[22];  // col_wo
  srcs.p[10] = (const float*)d_in[26]; // tr_w1
  srcs.p[11] = (const float*)d_in[28]; // tr_w2

  dim3 b256(256);
  transpose_all<<<dim3(4608), b256, 0, stream>>>(srcs, wt);
  pair_bias_kernel<<<dim3(2048), b256, 0, stream>>>(z, row_z_ln_w, row_z_ln_b,
                                                    (const float*)d_in[10], pb);

  // ---- row attention ----
  ln_kernel<false><<<dim3(8192), b256, 0, stream>>>(m, row_ln_w, row_ln_b, bx);
  gemm128<true,true,false,0,false,1><<<dim3(8,256), b256, 0, stream>>>(
      bx, wt, row_bg, nullptr, fq, 32768, 1024, 256, 768);
  // row: token = s*256 + q; base per outer(s) = s*256*32 = s*8192
  atten_kernel<256,true><<<dim3(1024), b256, 0, stream>>>(
      fq, fq + 8 * HSEC, fq + 16 * HSEC, fq + 24 * HSEC, pb, m_mask, t_o,
      8192, 65536, 256, 256, 1);
  gemm128<true,false,false,1,false,0><<<dim3(2,256), b256, 0, stream>>>(
      t_o, wt + 262144, row_bo, m, bx, 32768, 256, 256, 0);   // m1 -> bx (bf16)

  // ---- column attention ----
  ln_kernel<true><<<dim3(8192), b256, 0, stream>>>(bx, col_ln_w, col_ln_b, t_o);
  gemm128<true,true,false,0,false,2><<<dim3(8,256), b256, 0, stream>>>(
      t_o, wt + 327680, col_bg, nullptr, fq, 32768, 1024, 256, 768);
  // col: token' = r*128 + s; base per outer(r) = r*128*32 = r*4096; output row = s*256 + r
  atten_kernel<128,false><<<dim3(2048), b256, 0, stream>>>(
      fq, fq + 8 * HSEC, fq + 16 * HSEC, fq + 24 * HSEC, nullptr, m_mask, t_o,
      4096, 256, 65536, 1, 256);
  gemm128<true,false,false,2,false,0><<<dim3(2,256), b256, 0, stream>>>(
      t_o, wt + 589824, col_bo, bx, m2, 32768, 256, 256, 0);  // m2 -> fq[0..] (bf16)

  // ---- transition ----
  ln_kernel<true><<<dim3(8192), b256, 0, stream>>>(m2, tr_ln_w, tr_ln_b, bx);
  gemm128<true,false,true,0,false,0><<<dim3(8,256), b256, 0, stream>>>(
      bx, wt + 655360, tr_b1, nullptr, h1, 32768, 1024, 256, 0);
  gemm128<true,false,false,2,true,0><<<dim3(2,256), b256, 0, stream>>>(
      h1, wt + 917504, tr_b2, m2, out, 32768, 256, 1024, 0);
}